// Round 1
// baseline (278.760 us; speedup 1.0000x reference)
//
#include <hip/hip_runtime.h>

// ---------------------------------------------------------------------------
// GeneratorInitial: filters MLP -> conv9x9(relu) -> per-sample depthwise 3x3
//                   -> conv9x9(relu) -> pixnorm.  All f32, NHWC, C=4.
// ---------------------------------------------------------------------------

#define FMA4(A, S, W)                         \
    do {                                      \
        (A).x = fmaf((S), (W).x, (A).x);      \
        (A).y = fmaf((S), (W).y, (A).y);      \
        (A).z = fmaf((S), (W).z, (A).z);      \
        (A).w = fmaf((S), (W).w, (A).w);      \
    } while (0)

#define FMA4V(A, V, W)                        \
    do {                                      \
        (A).x = fmaf((V).x, (W).x, (A).x);    \
        (A).y = fmaf((V).y, (W).y, (A).y);    \
        (A).z = fmaf((V).z, (W).z, (A).z);    \
        (A).w = fmaf((V).w, (W).w, (A).w);    \
    } while (0)

static __device__ __forceinline__ float silu_f(float x) {
    return x / (1.0f + expf(-x));
}

// --- tiny kernel: emb = silu(params @ W_emb + b_emb); filters = silu(emb . KT + bT)
__global__ __launch_bounds__(256) void k_filters(
    const float* __restrict__ params,  // [16,8]
    const float* __restrict__ W_emb,   // [8,128]
    const float* __restrict__ b_emb,   // [128]
    const float* __restrict__ KT,      // [3,3,128,4]
    const float* __restrict__ bT,      // [4]
    float* __restrict__ filt)          // [16,3,3,4]
{
    __shared__ float s_emb[2048];
    const int t = threadIdx.x;
    for (int idx = t; idx < 2048; idx += 256) {
        const int b = idx >> 7, e = idx & 127;
        float s = b_emb[e];
#pragma unroll
        for (int p = 0; p < 8; ++p)
            s = fmaf(params[b * 8 + p], W_emb[p * 128 + e], s);
        s_emb[idx] = silu_f(s);
    }
    __syncthreads();
    for (int idx = t; idx < 576; idx += 256) {
        const int b = idx / 36, rem = idx % 36;
        const int ij = rem >> 2, f = rem & 3;
        float s = bT[f];
        for (int c = 0; c < 128; ++c)
            s = fmaf(s_emb[b * 128 + c], KT[(ij * 128 + c) * 4 + f], s);
        filt[idx] = silu_f(s);
    }
}

// --- shared 9x9x4->4 tile conv: src is a [40][41] float4 LDS tile,
//     sw is [dy][dx][c] -> float4 over out-channels (324 entries).
//     Thread computes 4 consecutive x pixels at (r, g..g+3).
static __device__ __forceinline__ void conv9x9(
    const float4 (*__restrict__ src)[41],
    const float4* __restrict__ sw,
    const float4 bias, const int r, const int g,
    float4& a0, float4& a1, float4& a2, float4& a3)
{
    a0 = bias; a1 = bias; a2 = bias; a3 = bias;
    for (int dy = 0; dy < 9; ++dy) {
        float rowf[48];
#pragma unroll
        for (int k = 0; k < 12; ++k) {
            const float4 v = src[r + dy][g + k];
            rowf[4 * k + 0] = v.x;
            rowf[4 * k + 1] = v.y;
            rowf[4 * k + 2] = v.z;
            rowf[4 * k + 3] = v.w;
        }
#pragma unroll
        for (int dx = 0; dx < 9; ++dx) {
#pragma unroll
            for (int c = 0; c < 4; ++c) {
                const float4 w = sw[(dy * 9 + dx) * 4 + c];
                FMA4(a0, rowf[(dx + 0) * 4 + c], w);
                FMA4(a1, rowf[(dx + 1) * 4 + c], w);
                FMA4(a2, rowf[(dx + 2) * 4 + c], w);
                FMA4(a3, rowf[(dx + 3) * 4 + c], w);
            }
        }
    }
}

// --- conv1: [16,512,512,4] -> relu -> y1 [16,504,504,4]
__global__ __launch_bounds__(256) void k_conv1(
    const float* __restrict__ in, const float* __restrict__ W1,
    const float* __restrict__ b1, float* __restrict__ y1)
{
    __shared__ float4 s_in[40][41];
    __shared__ float4 s_w[324];
    const int t = threadIdx.x;
    const int ox = blockIdx.x * 32, oy = blockIdx.y * 32, b = blockIdx.z;

    for (int i = t; i < 324; i += 256) s_w[i] = ((const float4*)W1)[i];
    const float4 bias = *(const float4*)b1;

    const float4* inp = (const float4*)in + (size_t)b * (512 * 512);
    for (int i = t; i < 1600; i += 256) {
        const int rr = i / 40, cc = i % 40;
        const int gy = oy + rr, gx = ox + cc;
        float4 v = make_float4(0.f, 0.f, 0.f, 0.f);
        if (gy < 512 && gx < 512) v = inp[gy * 512 + gx];
        s_in[rr][cc] = v;
    }
    __syncthreads();

    const int r = t >> 3, g = (t & 7) * 4;
    float4 a0, a1, a2, a3;
    conv9x9(s_in, s_w, bias, r, g, a0, a1, a2, a3);

    const int Y = oy + r;
    if (Y >= 504) return;
    float4* op = (float4*)y1 + (size_t)b * (504 * 504) + (size_t)Y * 504;
    const int X = ox + g;
    float4 av[4] = {a0, a1, a2, a3};
#pragma unroll
    for (int p = 0; p < 4; ++p) {
        if (X + p < 504) {
            float4 v = av[p];
            v.x = fmaxf(v.x, 0.f); v.y = fmaxf(v.y, 0.f);
            v.z = fmaxf(v.z, 0.f); v.w = fmaxf(v.w, 0.f);
            op[X + p] = v;
        }
    }
}

// --- fused: per-sample depthwise 3x3 SAME on y1, then conv2 9x9 valid + relu
//     + pixnorm -> out [16,496,496,4]
__global__ __launch_bounds__(256) void k_dwconv2(
    const float* __restrict__ y1, const float* __restrict__ filt,
    const float* __restrict__ W2, const float* __restrict__ b2,
    float* __restrict__ out)
{
    __shared__ float4 s_y1[42][43];
    __shared__ float4 s_y2[40][41];
    __shared__ float4 s_w[324];
    const int t = threadIdx.x;
    const int tx = blockIdx.x * 32, ty = blockIdx.y * 32, b = blockIdx.z;

    for (int i = t; i < 324; i += 256) s_w[i] = ((const float4*)W2)[i];
    const float4 bias = *(const float4*)b2;

    const float4* yp = (const float4*)y1 + (size_t)b * (504 * 504);
    for (int i = t; i < 42 * 42; i += 256) {
        const int rr = i / 42, cc = i % 42;
        const int gy = ty - 1 + rr, gx = tx - 1 + cc;
        float4 v = make_float4(0.f, 0.f, 0.f, 0.f);
        if (gy >= 0 && gy < 504 && gx >= 0 && gx < 504) v = yp[gy * 504 + gx];
        s_y1[rr][cc] = v;
    }
    float4 f4[9];
    const float4* fp = (const float4*)filt + b * 9;
#pragma unroll
    for (int i = 0; i < 9; ++i) f4[i] = fp[i];
    __syncthreads();

    // depthwise 3x3 (SAME padding handled by the zero-filled halo)
    for (int i = t; i < 1600; i += 256) {
        const int p = i / 40, q = i % 40;
        float4 a = make_float4(0.f, 0.f, 0.f, 0.f);
#pragma unroll
        for (int ij = 0; ij < 9; ++ij) {
            const float4 v = s_y1[p + ij / 3][q + ij % 3];
            FMA4V(a, v, f4[ij]);
        }
        s_y2[p][q] = a;
    }
    __syncthreads();

    const int r = t >> 3, g = (t & 7) * 4;
    float4 a0, a1, a2, a3;
    conv9x9(s_y2, s_w, bias, r, g, a0, a1, a2, a3);

    const int Y = ty + r;
    if (Y >= 496) return;
    float4* op = (float4*)out + (size_t)b * (496 * 496) + (size_t)Y * 496;
    const int X = tx + g;
    float4 av[4] = {a0, a1, a2, a3};
#pragma unroll
    for (int p = 0; p < 4; ++p) {
        if (X + p < 496) {
            float4 v = av[p];
            v.x = fmaxf(v.x, 0.f); v.y = fmaxf(v.y, 0.f);
            v.z = fmaxf(v.z, 0.f); v.w = fmaxf(v.w, 0.f);
            const float ms =
                fmaf(v.x, v.x, fmaf(v.y, v.y, fmaf(v.z, v.z, v.w * v.w))) * 0.25f
                + 1e-8f;
            const float s = rsqrtf(ms);
            v.x *= s; v.y *= s; v.z *= s; v.w *= s;
            op[X + p] = v;
        }
    }
}

extern "C" void kernel_launch(void* const* d_in, const int* in_sizes, int n_in,
                              void* d_out, int out_size, void* d_ws, size_t ws_size,
                              hipStream_t stream)
{
    const float* noise  = (const float*)d_in[0];
    const float* params = (const float*)d_in[1];
    const float* W_emb  = (const float*)d_in[2];
    const float* b_emb  = (const float*)d_in[3];
    const float* KT     = (const float*)d_in[4];
    const float* bT     = (const float*)d_in[5];
    const float* W1     = (const float*)d_in[6];
    const float* b1     = (const float*)d_in[7];
    const float* W2     = (const float*)d_in[8];
    const float* b2     = (const float*)d_in[9];

    float* out  = (float*)d_out;
    float* y1   = (float*)d_ws;                                   // 16*504*504*4 f32 = 65 MB
    float* filt = (float*)((char*)d_ws +
                           (size_t)16 * 504 * 504 * 4 * sizeof(float)); // [16,3,3,4]

    k_filters<<<dim3(1), dim3(256), 0, stream>>>(params, W_emb, b_emb, KT, bT, filt);

    dim3 grid(16, 16, 16);  // ceil(504/32), ceil(504/32), B
    k_conv1<<<grid, dim3(256), 0, stream>>>(noise, W1, b1, y1);

    dim3 grid2(16, 16, 16); // ceil(496/32), ceil(496/32), B
    k_dwconv2<<<grid2, dim3(256), 0, stream>>>(y1, filt, W2, b2, out);
}

// Round 4
// 217.157 us; speedup vs baseline: 1.2837x; 1.2837x over previous
//
#include <hip/hip_runtime.h>

// ---------------------------------------------------------------------------
// GeneratorInitial via split-f16 MFMA (hi/lo decomposition, f32-class accuracy)
//   x = hi + lo  (hi = f16(x), lo = f16(x-hi));  conv uses
//   ah*Bh + ah*Bl + al*Bh  (exact f16 products, f32 accumulate).
//   k_conv1:   in f32 -> conv 9x9 -> relu -> y1 as interleaved (hi,lo) f16
//   k_dwconv2: filter-MLP + depthwise 3x3 (f32) + conv 9x9 + relu + pixnorm
//
// MFMA scheme per output row: 9 dy-rowconvs, each M16 x N16 x K64:
//   M = 16 pixel groups (x stride 4), N = (shift s 0..3) x (out ch f 0..3),
//   K = 16 e-positions x 4 in-ch.  B[k=(e,c)][n=(s,f)] = W[dy][e-s][c][f].
// ---------------------------------------------------------------------------

typedef _Float16 f16;
typedef _Float16 f16x2 __attribute__((ext_vector_type(2)));
typedef _Float16 f16x4 __attribute__((ext_vector_type(4)));
typedef _Float16 f16x8 __attribute__((ext_vector_type(8)));
typedef float f32x4 __attribute__((ext_vector_type(4)));

static __device__ __forceinline__ f32x4 mfma16(f16x8 a, f16x8 b, f32x4 c) {
    return __builtin_amdgcn_mfma_f32_16x16x32_f16(a, b, c, 0, 0, 0);
}

static __device__ __forceinline__ float silu_f(float x) {
    return x / (1.0f + expf(-x));
}

// returns (hi, lo) with x == hi + lo to f32 precision of the split
static __device__ __forceinline__ f16x2 split_f(float x) {
    f16x2 r;
    r[0] = (f16)x;
    r[1] = (f16)(x - (float)r[0]);
    return r;
}

// Build hi/lo B fragments (Bh[9][2], Bl[9][2]) from a 9x9x4x4 weight tensor.
// Uses g (lane>>4), s, f from enclosing scope.
#define BUILD_BFRAGS(Wsrc)                                                    \
    do {                                                                      \
        _Pragma("unroll") for (int dy = 0; dy < 9; ++dy) {                    \
            _Pragma("unroll") for (int st = 0; st < 2; ++st) {                \
                f16x8 bh, bl;                                                 \
                _Pragma("unroll") for (int j = 0; j < 8; ++j) {               \
                    const int k = st * 32 + g * 8 + j;                        \
                    const int e = k >> 2, c = k & 3, dx = e - s;              \
                    const float wv = (dx >= 0 && dx < 9)                      \
                        ? (Wsrc)[((dy * 9 + dx) * 4 + c) * 4 + f] : 0.f;      \
                    const f16x2 hl = split_f(wv);                             \
                    bh[j] = hl[0]; bl[j] = hl[1];                             \
                }                                                             \
                Bh[dy][st] = bh; Bl[dy][st] = bl;                             \
            }                                                                 \
        }                                                                     \
    } while (0)

// 6-term split MFMA accumulation for one (row, dy)
#define ACC_STEP(ACC, DY)                                                     \
    do {                                                                      \
        (ACC) = mfma16(ah0, Bh[DY][0], (ACC));                                \
        (ACC) = mfma16(ah1, Bh[DY][1], (ACC));                                \
        (ACC) = mfma16(ah0, Bl[DY][0], (ACC));                                \
        (ACC) = mfma16(ah1, Bl[DY][1], (ACC));                                \
        (ACC) = mfma16(al0, Bh[DY][0], (ACC));                                \
        (ACC) = mfma16(al1, Bh[DY][1], (ACC));                                \
    } while (0)

// --- conv1: [16,512,512,4] f32 -> relu -> y1 [16,504,504] x 8 f16/pixel
//     y1 pixel layout: [h0,l0,h1,l1,h2,l2,h3,l3]
__global__ __launch_bounds__(256, 2) void k_conv1(
    const float* __restrict__ in, const float* __restrict__ W1,
    const float* __restrict__ b1, f16* __restrict__ y1)
{
    __shared__ f16x4 s_hi[24][76];
    __shared__ f16x4 s_lo[24][76];
    const int t = threadIdx.x;
    const int x0 = blockIdx.x * 64, y0 = blockIdx.y * 16, b = blockIdx.z;

    const float4* inp = (const float4*)in + (size_t)b * (512 * 512);
    for (int i = t; i < 24 * 76; i += 256) {
        const int rr = i / 76, cc = i % 76;
        const int gy = y0 + rr, gx = x0 + cc;
        float4 v = make_float4(0.f, 0.f, 0.f, 0.f);
        if (gy < 512 && gx < 512) v = inp[gy * 512 + gx];
        f16x4 h, l;
        f16x2 p0 = split_f(v.x), p1 = split_f(v.y);
        f16x2 p2 = split_f(v.z), p3 = split_f(v.w);
        h[0] = p0[0]; l[0] = p0[1];
        h[1] = p1[0]; l[1] = p1[1];
        h[2] = p2[0]; l[2] = p2[1];
        h[3] = p3[0]; l[3] = p3[1];
        s_hi[rr][cc] = h; s_lo[rr][cc] = l;
    }

    const int lane = t & 63, w = t >> 6;
    const int g = lane >> 4, n = lane & 15, s = n >> 2, f = n & 3;
    f16x8 Bh[9][2], Bl[9][2];
    BUILD_BFRAGS(W1);

    __syncthreads();

    const float bias = b1[f];
    f32x4 acc[4];
#pragma unroll
    for (int r = 0; r < 4; ++r) acc[r] = (f32x4){bias, bias, bias, bias};

    const int ai = 4 * (lane & 15) + 2 * g;
#pragma unroll
    for (int ir = 0; ir < 12; ++ir) {
        const f16x4* rh = &s_hi[w * 4 + ir][0];
        const f16x4* rl = &s_lo[w * 4 + ir][0];
        const f16x8 ah0 = *(const f16x8*)(rh + ai);
        const f16x8 ah1 = *(const f16x8*)(rh + ai + 8);
        const f16x8 al0 = *(const f16x8*)(rl + ai);
        const f16x8 al1 = *(const f16x8*)(rl + ai + 8);
#pragma unroll
        for (int r = 0; r < 4; ++r) {
            const int dy = ir - r;
            if (dy >= 0 && dy < 9) ACC_STEP(acc[r], dy);
        }
    }

    // D: col n=(s,f)=lane&15; row m=(lane>>4)*4+q.  x = x0 + 4m + s.
    const int xb = x0 + 16 * g + s;
#pragma unroll
    for (int r = 0; r < 4; ++r) {
        const int yr = y0 + w * 4 + r;
        if (yr >= 504) continue;
        const size_t rowbase = ((size_t)(b * 504 + yr) * 504) * 8 + f * 2;
#pragma unroll
        for (int q = 0; q < 4; ++q) {
            const int x = xb + 4 * q;
            if (x < 504) {
                const float v = fmaxf(acc[r][q], 0.f);
                *(f16x2*)(y1 + rowbase + (size_t)x * 8) = split_f(v);
            }
        }
    }
}

// --- fused: filter MLP + per-sample depthwise 3x3 SAME (f32) + conv2 9x9
//     valid + relu + pixnorm -> out [16,496,496,4] f32
__global__ __launch_bounds__(256, 2) void k_dwconv2(
    const f16* __restrict__ y1,
    const float* __restrict__ params, const float* __restrict__ W_emb,
    const float* __restrict__ b_emb, const float* __restrict__ KT,
    const float* __restrict__ bT,
    const float* __restrict__ W2, const float* __restrict__ b2,
    float* __restrict__ out)
{
    __shared__ float4 s_x[26][78];   // reconstructed f32 y1 tile (halo 1)
    __shared__ f16x4 s_dh[24][76];   // depthwise result hi
    __shared__ f16x4 s_dl[24][76];   // depthwise result lo
    __shared__ float s_emb[128];
    __shared__ float s_filt[36];

    const int t = threadIdx.x;
    const int x0 = blockIdx.x * 64, y0 = blockIdx.y * 16, b = blockIdx.z;

    // stage y1 tile with halo of 1 (zero pad outside [0,504)^2), f32 reconstruct
    for (int i = t; i < 26 * 78; i += 256) {
        const int rr = i / 78, cc = i % 78;
        const int gy = y0 - 1 + rr, gx = x0 - 1 + cc;
        float4 v = make_float4(0.f, 0.f, 0.f, 0.f);
        if (gy >= 0 && gy < 504 && gx >= 0 && gx < 504) {
            const f16x8 p = *(const f16x8*)(y1 + ((size_t)(b * 504 + gy) * 504 +
                                                  (size_t)gx) * 8);
            v.x = (float)p[0] + (float)p[1];
            v.y = (float)p[2] + (float)p[3];
            v.z = (float)p[4] + (float)p[5];
            v.w = (float)p[6] + (float)p[7];
        }
        s_x[rr][cc] = v;
    }

    // filter MLP
    if (t < 128) {
        float sv = b_emb[t];
#pragma unroll
        for (int p = 0; p < 8; ++p)
            sv = fmaf(params[b * 8 + p], W_emb[p * 128 + t], sv);
        s_emb[t] = silu_f(sv);
    }
    __syncthreads();
    if (t < 36) {
        const int ij = t >> 2, ff = t & 3;
        float sv = bT[ff];
        for (int c = 0; c < 128; ++c)
            sv = fmaf(s_emb[c], KT[(ij * 128 + c) * 4 + ff], sv);
        s_filt[t] = silu_f(sv);
    }
    __syncthreads();

    float fw[9][4];
#pragma unroll
    for (int ij = 0; ij < 9; ++ij)
#pragma unroll
        for (int c = 0; c < 4; ++c) fw[ij][c] = s_filt[ij * 4 + c];

    // depthwise 3x3 in f32, split result to hi/lo
    for (int i = t; i < 24 * 76; i += 256) {
        const int p = i / 76, q = i % 76;
        float a0 = 0.f, a1 = 0.f, a2 = 0.f, a3 = 0.f;
#pragma unroll
        for (int ij = 0; ij < 9; ++ij) {
            const float4 v = s_x[p + ij / 3][q + ij % 3];
            a0 = fmaf(v.x, fw[ij][0], a0);
            a1 = fmaf(v.y, fw[ij][1], a1);
            a2 = fmaf(v.z, fw[ij][2], a2);
            a3 = fmaf(v.w, fw[ij][3], a3);
        }
        f16x4 h, l;
        f16x2 p0 = split_f(a0), p1 = split_f(a1);
        f16x2 p2 = split_f(a2), p3 = split_f(a3);
        h[0] = p0[0]; l[0] = p0[1];
        h[1] = p1[0]; l[1] = p1[1];
        h[2] = p2[0]; l[2] = p2[1];
        h[3] = p3[0]; l[3] = p3[1];
        s_dh[p][q] = h; s_dl[p][q] = l;
    }

    const int lane = t & 63, w = t >> 6;
    const int g = lane >> 4, n = lane & 15, s = n >> 2, f = n & 3;
    f16x8 Bh[9][2], Bl[9][2];
    BUILD_BFRAGS(W2);

    __syncthreads();

    const float bias = b2[f];
    f32x4 acc[4];
#pragma unroll
    for (int r = 0; r < 4; ++r) acc[r] = (f32x4){bias, bias, bias, bias};

    const int ai = 4 * (lane & 15) + 2 * g;
#pragma unroll
    for (int ir = 0; ir < 12; ++ir) {
        const f16x4* rh = &s_dh[w * 4 + ir][0];
        const f16x4* rl = &s_dl[w * 4 + ir][0];
        const f16x8 ah0 = *(const f16x8*)(rh + ai);
        const f16x8 ah1 = *(const f16x8*)(rh + ai + 8);
        const f16x8 al0 = *(const f16x8*)(rl + ai);
        const f16x8 al1 = *(const f16x8*)(rl + ai + 8);
#pragma unroll
        for (int r = 0; r < 4; ++r) {
            const int dy = ir - r;
            if (dy >= 0 && dy < 9) ACC_STEP(acc[r], dy);
        }
    }

    // epilogue: relu -> pixnorm across channels (lanes l^1, l^2) -> f32 store
    const int xb = x0 + 16 * g + s;
#pragma unroll
    for (int r = 0; r < 4; ++r) {
        const int yr = y0 + w * 4 + r;
        const size_t rowbase = ((size_t)((size_t)b * 496 + yr) * 496) * 4 + f;
#pragma unroll
        for (int q = 0; q < 4; ++q) {
            float v = fmaxf(acc[r][q], 0.f);
            float sq = v * v;
            sq += __shfl_xor(sq, 1);
            sq += __shfl_xor(sq, 2);
            const float sc = rsqrtf(sq * 0.25f + 1e-8f);
            const int x = xb + 4 * q;
            if (yr < 496 && x < 496) out[rowbase + (size_t)x * 4] = v * sc;
        }
    }
}

extern "C" void kernel_launch(void* const* d_in, const int* in_sizes, int n_in,
                              void* d_out, int out_size, void* d_ws, size_t ws_size,
                              hipStream_t stream)
{
    const float* noise  = (const float*)d_in[0];
    const float* params = (const float*)d_in[1];
    const float* W_emb  = (const float*)d_in[2];
    const float* b_emb  = (const float*)d_in[3];
    const float* KT     = (const float*)d_in[4];
    const float* bT     = (const float*)d_in[5];
    const float* W1     = (const float*)d_in[6];
    const float* b1     = (const float*)d_in[7];
    const float* W2     = (const float*)d_in[8];
    const float* b2     = (const float*)d_in[9];

    float* out = (float*)d_out;
    f16*   y1  = (f16*)d_ws;  // 16*504*504*8 f16 = 65 MB (hi/lo interleaved)

    dim3 grid(8, 32, 16);   // ceil(504/64), ceil(504/16), B
    k_conv1<<<grid, dim3(256), 0, stream>>>(noise, W1, b1, y1);

    dim3 grid2(8, 31, 16);  // ceil(496/64), 496/16, B
    k_dwconv2<<<grid2, dim3(256), 0, stream>>>(y1, params, W_emb, b_emb, KT, bT,
                                               W2, b2, out);
}

// Round 5
// 149.861 us; speedup vs baseline: 1.8601x; 1.4491x over previous
//
#include <hip/hip_runtime.h>

// ---------------------------------------------------------------------------
// GeneratorInitial via split-f16 MFMA (hi/lo, f32-class accuracy) with the
// depthwise 3x3 folded into conv2 as a per-batch composite 11x11 conv:
//   out = W2 (*) (F_b (*) y1) = Wc_b (*) y1,  Wc_b = F_b (*) W2  (both linear)
//
//   k_prep:    filter MLP -> F_b; Wc_b = F_b (*) W2; emit pre-split per-lane
//              MFMA B-fragments for W1 (9 dy) and Wc_b (11 dy).
//   k_conv1:   in f32 -> 9x9 conv (MFMA) -> relu -> y1 (hi,lo f16 interleaved)
//   k_dwconv2: y1 -> 11x11 per-batch conv (MFMA) -> relu -> pixnorm -> out
//
// MFMA scheme per output row: dy-rowconvs, each M16 x N16 x K64:
//   M = 16 pixel groups (x stride 4), N = (shift s 0..3) x (out ch f 0..3),
//   K = 16 e-positions x 4 in-ch, k = st*32 + 8g + j.  B[k][n] = W[dy][e-s][c][f].
// ---------------------------------------------------------------------------

typedef _Float16 f16;
typedef _Float16 f16x2 __attribute__((ext_vector_type(2)));
typedef _Float16 f16x4 __attribute__((ext_vector_type(4)));
typedef _Float16 f16x8 __attribute__((ext_vector_type(8)));
typedef float f32x4 __attribute__((ext_vector_type(4)));

static __device__ __forceinline__ f32x4 mfma16(f16x8 a, f16x8 b, f32x4 c) {
    return __builtin_amdgcn_mfma_f32_16x16x32_f16(a, b, c, 0, 0, 0);
}

static __device__ __forceinline__ float silu_f(float x) {
    return x / (1.0f + expf(-x));
}

// returns (hi, lo) with x ~= hi + lo
static __device__ __forceinline__ f16x2 split_f(float x) {
    f16x2 r;
    r[0] = (f16)x;
    r[1] = (f16)(x - (float)r[0]);
    return r;
}

// 6-term split MFMA accumulation for one (row, dy)
#define ACC_STEP(ACC, DY)                                                     \
    do {                                                                      \
        (ACC) = mfma16(ah0, Bh[DY][0], (ACC));                                \
        (ACC) = mfma16(ah1, Bh[DY][1], (ACC));                                \
        (ACC) = mfma16(ah0, Bl[DY][0], (ACC));                                \
        (ACC) = mfma16(ah1, Bl[DY][1], (ACC));                                \
        (ACC) = mfma16(al0, Bh[DY][0], (ACC));                                \
        (ACC) = mfma16(al1, Bh[DY][1], (ACC));                                \
    } while (0)

// --- prep: per-batch filters, composite weights, pre-split B-fragments
//     fragW1: [9][st 2][hl 2][lane 64] f16x8      (batch-independent)
//     fragW2: [16][11][st 2][hl 2][lane 64] f16x8 (per-batch composite)
__global__ __launch_bounds__(256) void k_prep(
    const float* __restrict__ params, const float* __restrict__ W_emb,
    const float* __restrict__ b_emb, const float* __restrict__ KT,
    const float* __restrict__ bT, const float* __restrict__ W1,
    const float* __restrict__ W2,
    f16x8* __restrict__ fragW1, f16x8* __restrict__ fragW2)
{
    __shared__ float s_emb[128];
    __shared__ float s_filt[36];      // [i2*3+j2][c]
    __shared__ float s_wc[1936];      // [dy][dx][c][f], 11x11x4x4
    const int t = threadIdx.x, b = blockIdx.x;

    if (t < 128) {
        float sv = b_emb[t];
#pragma unroll
        for (int p = 0; p < 8; ++p)
            sv = fmaf(params[b * 8 + p], W_emb[p * 128 + t], sv);
        s_emb[t] = silu_f(sv);
    }
    __syncthreads();
    if (t < 36) {
        const int ij = t >> 2, ff = t & 3;
        float sv = bT[ff];
        for (int c = 0; c < 128; ++c)
            sv = fmaf(s_emb[c], KT[(ij * 128 + c) * 4 + ff], sv);
        s_filt[t] = silu_f(sv);
    }
    __syncthreads();

    // composite Wc[dy][dx][c][f] = sum_{i2,j2} F[i2][j2][c] * W2[dy-i2][dx-j2][c][f]
    for (int i = t; i < 1936; i += 256) {
        const int f = i & 3, c = (i >> 2) & 3;
        const int dxy = i >> 4, dx = dxy % 11, dy = dxy / 11;
        float sv = 0.f;
#pragma unroll
        for (int i2 = 0; i2 < 3; ++i2)
#pragma unroll
            for (int j2 = 0; j2 < 3; ++j2) {
                const int a = dy - i2, bb = dx - j2;
                if (a >= 0 && a < 9 && bb >= 0 && bb < 9)
                    sv = fmaf(s_filt[(i2 * 3 + j2) * 4 + c],
                              W2[((a * 9 + bb) * 4 + c) * 4 + f], sv);
            }
        s_wc[i] = sv;
    }
    __syncthreads();

    // B-fragments for the composite (per batch)
    for (int fi = t; fi < 11 * 256; fi += 256) {
        const int dy = fi >> 8, rem = fi & 255;
        const int st = (rem >> 7) & 1, hl = (rem >> 6) & 1, lane = rem & 63;
        const int g = lane >> 4, n = lane & 15, s = n >> 2, f = n & 3;
        f16x8 v;
#pragma unroll
        for (int j = 0; j < 8; ++j) {
            const int k = st * 32 + g * 8 + j;
            const int e = k >> 2, c = k & 3, dx = e - s;
            const float wv = (dx >= 0 && dx < 11)
                ? s_wc[((dy * 11 + dx) * 4 + c) * 4 + f] : 0.f;
            const f16x2 hlv = split_f(wv);
            v[j] = hl ? hlv[1] : hlv[0];
        }
        fragW2[((size_t)b * 11 + dy) * 256 + rem] = v;
    }

    // B-fragments for W1 (batch-independent; block 0 only)
    if (b == 0) {
        for (int fi = t; fi < 9 * 256; fi += 256) {
            const int dy = fi >> 8, rem = fi & 255;
            const int st = (rem >> 7) & 1, hl = (rem >> 6) & 1, lane = rem & 63;
            const int g = lane >> 4, n = lane & 15, s = n >> 2, f = n & 3;
            f16x8 v;
#pragma unroll
            for (int j = 0; j < 8; ++j) {
                const int k = st * 32 + g * 8 + j;
                const int e = k >> 2, c = k & 3, dx = e - s;
                const float wv = (dx >= 0 && dx < 9)
                    ? W1[((dy * 9 + dx) * 4 + c) * 4 + f] : 0.f;
                const f16x2 hlv = split_f(wv);
                v[j] = hl ? hlv[1] : hlv[0];
            }
            fragW1[(size_t)dy * 256 + rem] = v;
        }
    }
}

// --- conv1: [16,512,512,4] f32 -> relu -> y1 [16,504,504] x (h,l)x4 f16
__global__ __launch_bounds__(256, 2) void k_conv1(
    const float* __restrict__ in, const float* __restrict__ b1,
    const f16x8* __restrict__ fragW1, f16* __restrict__ y1)
{
    __shared__ f16x4 s_hi[40][76];
    __shared__ f16x4 s_lo[40][76];
    const int t = threadIdx.x;
    const int x0 = blockIdx.x * 64, y0 = blockIdx.y * 32, b = blockIdx.z;

    const float4* inp = (const float4*)in + (size_t)b * (512 * 512);
    for (int i = t; i < 40 * 76; i += 256) {
        const int rr = i / 76, cc = i % 76;
        const int gy = y0 + rr, gx = x0 + cc;
        float4 v = make_float4(0.f, 0.f, 0.f, 0.f);
        if (gy < 512 && gx < 512) v = inp[gy * 512 + gx];
        f16x4 h, l;
        const f16x2 p0 = split_f(v.x), p1 = split_f(v.y);
        const f16x2 p2 = split_f(v.z), p3 = split_f(v.w);
        h[0] = p0[0]; l[0] = p0[1]; h[1] = p1[0]; l[1] = p1[1];
        h[2] = p2[0]; l[2] = p2[1]; h[3] = p3[0]; l[3] = p3[1];
        s_hi[rr][cc] = h; s_lo[rr][cc] = l;
    }

    const int lane = t & 63, w = t >> 6;
    const int g = lane >> 4, n = lane & 15, s = n >> 2, f = n & 3;

    f16x8 Bh[9][2], Bl[9][2];
#pragma unroll
    for (int dy = 0; dy < 9; ++dy)
#pragma unroll
        for (int st = 0; st < 2; ++st) {
            Bh[dy][st] = fragW1[dy * 256 + st * 128 + lane];
            Bl[dy][st] = fragW1[dy * 256 + st * 128 + 64 + lane];
        }

    __syncthreads();

    const float bias = b1[f];
    f32x4 acc[8];
#pragma unroll
    for (int r = 0; r < 8; ++r) acc[r] = (f32x4){bias, bias, bias, bias};

    const int ai = 4 * (lane & 15) + 2 * g;
#pragma unroll
    for (int ir = 0; ir < 16; ++ir) {
        const f16x4* rh = &s_hi[w * 8 + ir][0];
        const f16x4* rl = &s_lo[w * 8 + ir][0];
        const f16x8 ah0 = *(const f16x8*)(rh + ai);
        const f16x8 ah1 = *(const f16x8*)(rh + ai + 8);
        const f16x8 al0 = *(const f16x8*)(rl + ai);
        const f16x8 al1 = *(const f16x8*)(rl + ai + 8);
#pragma unroll
        for (int r = 0; r < 8; ++r) {
            const int dy = ir - r;
            if (dy >= 0 && dy < 9) ACC_STEP(acc[r], dy);
        }
    }

    // D: col n=(s,f); row m=4g+q; x = x0+16g+4q+s; store (h,l) f16x2
    const int xb = x0 + 16 * g + s;
#pragma unroll
    for (int r = 0; r < 8; ++r) {
        const int yr = y0 + w * 8 + r;
        if (yr >= 504) continue;
        const size_t rowbase = ((size_t)(b * 504 + yr) * 504) * 8 + f * 2;
#pragma unroll
        for (int q = 0; q < 4; ++q) {
            const int x = xb + 4 * q;
            if (x < 504) {
                const float v = fmaxf(acc[r][q], 0.f);
                *(f16x2*)(y1 + rowbase + (size_t)x * 8) = split_f(v);
            }
        }
    }
}

// --- composite 11x11 per-batch conv on y1 + relu + pixnorm -> out f32
__global__ __launch_bounds__(256, 2) void k_dwconv2(
    const f16* __restrict__ y1, const float* __restrict__ b2,
    const f16x8* __restrict__ fragW2, float* __restrict__ out)
{
    __shared__ f16x4 s_hi[42][76];
    __shared__ f16x4 s_lo[42][76];
    const int t = threadIdx.x;
    const int x0 = blockIdx.x * 64, y0 = blockIdx.y * 32, b = blockIdx.z;

    // stage y1 with halo (-1 .. +9 beyond tile), zero outside [0,504)^2
    for (int i = t; i < 42 * 76; i += 256) {
        const int rr = i / 76, cc = i % 76;
        const int gy = y0 - 1 + rr, gx = x0 - 1 + cc;
        f16x4 h, l;
        if (gy >= 0 && gy < 504 && gx >= 0 && gx < 504) {
            const f16x8 p = *(const f16x8*)(y1 + ((size_t)(b * 504 + gy) * 504 +
                                                  (size_t)gx) * 8);
            h[0] = p[0]; l[0] = p[1]; h[1] = p[2]; l[1] = p[3];
            h[2] = p[4]; l[2] = p[5]; h[3] = p[6]; l[3] = p[7];
        } else {
            h[0] = h[1] = h[2] = h[3] = (f16)0.f;
            l[0] = l[1] = l[2] = l[3] = (f16)0.f;
        }
        s_hi[rr][cc] = h; s_lo[rr][cc] = l;
    }

    const int lane = t & 63, w = t >> 6;
    const int g = lane >> 4, n = lane & 15, s = n >> 2, f = n & 3;

    const f16x8* fr = fragW2 + (size_t)b * 11 * 256;
    f16x8 Bh[11][2], Bl[11][2];
#pragma unroll
    for (int dy = 0; dy < 11; ++dy)
#pragma unroll
        for (int st = 0; st < 2; ++st) {
            Bh[dy][st] = fr[dy * 256 + st * 128 + lane];
            Bl[dy][st] = fr[dy * 256 + st * 128 + 64 + lane];
        }

    __syncthreads();

    const float bias = b2[f];
    f32x4 acc[8];
#pragma unroll
    for (int r = 0; r < 8; ++r) acc[r] = (f32x4){bias, bias, bias, bias};

    const int ai = 4 * (lane & 15) + 2 * g;
#pragma unroll
    for (int ir = 0; ir < 18; ++ir) {
        const f16x4* rh = &s_hi[w * 8 + ir][0];
        const f16x4* rl = &s_lo[w * 8 + ir][0];
        const f16x8 ah0 = *(const f16x8*)(rh + ai);
        const f16x8 ah1 = *(const f16x8*)(rh + ai + 8);
        const f16x8 al0 = *(const f16x8*)(rl + ai);
        const f16x8 al1 = *(const f16x8*)(rl + ai + 8);
#pragma unroll
        for (int r = 0; r < 8; ++r) {
            const int dy = ir - r;
            if (dy >= 0 && dy < 11) ACC_STEP(acc[r], dy);
        }
    }

    // epilogue: relu -> pixnorm across channels (lanes n^1, n^2) -> f32 store
    const int xb = x0 + 16 * g + s;
#pragma unroll
    for (int r = 0; r < 8; ++r) {
        const int yr = y0 + w * 8 + r;
        const size_t rowbase = ((size_t)((size_t)b * 496 + yr) * 496) * 4 + f;
#pragma unroll
        for (int q = 0; q < 4; ++q) {
            float v = fmaxf(acc[r][q], 0.f);
            float sq = v * v;
            sq += __shfl_xor(sq, 1);
            sq += __shfl_xor(sq, 2);
            const float sc = rsqrtf(sq * 0.25f + 1e-8f);
            const int x = xb + 4 * q;
            if (yr < 496 && x < 496) out[rowbase + (size_t)x * 4] = v * sc;
        }
    }
}

extern "C" void kernel_launch(void* const* d_in, const int* in_sizes, int n_in,
                              void* d_out, int out_size, void* d_ws, size_t ws_size,
                              hipStream_t stream)
{
    const float* noise  = (const float*)d_in[0];
    const float* params = (const float*)d_in[1];
    const float* W_emb  = (const float*)d_in[2];
    const float* b_emb  = (const float*)d_in[3];
    const float* KT     = (const float*)d_in[4];
    const float* bT     = (const float*)d_in[5];
    const float* W1     = (const float*)d_in[6];
    const float* b1     = (const float*)d_in[7];
    const float* W2     = (const float*)d_in[8];
    const float* b2     = (const float*)d_in[9];

    float* out = (float*)d_out;
    f16*   y1  = (f16*)d_ws;  // 16*504*504*8 f16 = 65,028,096 B
    f16x8* fragW2 = (f16x8*)((char*)d_ws + 65028096);           // 720,896 B
    f16x8* fragW1 = (f16x8*)((char*)d_ws + 65028096 + 720896);  //  36,864 B

    k_prep<<<dim3(16), dim3(256), 0, stream>>>(params, W_emb, b_emb, KT, bT,
                                               W1, W2, fragW1, fragW2);

    dim3 grid(8, 16, 16);   // ceil(504/64), ceil(504/32), B
    k_conv1<<<grid, dim3(256), 0, stream>>>(noise, b1, fragW1, y1);

    dim3 grid2(8, 16, 16);  // ceil(496/64), ceil(496/32), B
    k_dwconv2<<<grid2, dim3(256), 0, stream>>>(y1, b2, fragW2, out);
}

// Round 6
// 142.521 us; speedup vs baseline: 1.9559x; 1.0515x over previous
//
#include <hip/hip_runtime.h>

// ---------------------------------------------------------------------------
// GeneratorInitial via split-f16 MFMA (hi/lo, f32-class accuracy) with the
// depthwise 3x3 folded into conv2 as a per-batch composite 11x11 conv:
//   out = W2 (*) (F_b (*) y1) = Wc_b (*) y1,  Wc_b = F_b (*) W2  (both linear)
//
//   k_prep:    filter MLP -> F_b; Wc_b = F_b (*) W2; emit pre-split per-lane
//              MFMA B-fragments for W1 (9 dy) and Wc_b (11 dy).
//   k_conv1:   in f32 -> 9x9 conv (MFMA) -> relu -> y1 (hi,lo f16 interleaved)
//   k_dwconv2: y1 -> 11x11 per-batch conv (MFMA) -> relu -> pixnorm -> out
//
// MFMA scheme per output row: dy-rowconvs, each M16 x N16 x K64:
//   M = 16 pixel groups (x stride 4), N = (shift s 0..3) x (out ch f 0..3),
//   K = 16 e-positions x 4 in-ch, k = st*32 + 8g + j.  B[k][n] = W[dy][e-s][c][f].
// Register plan (per wave): A-fragments for all input rows resident
//   (2 K-half passes, acc carries), B-fragments streamed per dy from L2.
// ---------------------------------------------------------------------------

typedef _Float16 f16;
typedef _Float16 f16x2 __attribute__((ext_vector_type(2)));
typedef _Float16 f16x4 __attribute__((ext_vector_type(4)));
typedef _Float16 f16x8 __attribute__((ext_vector_type(8)));
typedef float f32x4 __attribute__((ext_vector_type(4)));

static __device__ __forceinline__ f32x4 mfma16(f16x8 a, f16x8 b, f32x4 c) {
    return __builtin_amdgcn_mfma_f32_16x16x32_f16(a, b, c, 0, 0, 0);
}

static __device__ __forceinline__ float silu_f(float x) {
    return x / (1.0f + expf(-x));
}

// returns (hi, lo) with x ~= hi + lo
static __device__ __forceinline__ f16x2 split_f(float x) {
    f16x2 r;
    r[0] = (f16)x;
    r[1] = (f16)(x - (float)r[0]);
    return r;
}

// --- prep: per-batch filters, composite weights, pre-split B-fragments
//     fragW1: [9][st 2][hl 2][lane 64] f16x8      (batch-independent)
//     fragW2: [16][11][st 2][hl 2][lane 64] f16x8 (per-batch composite)
__global__ __launch_bounds__(256) void k_prep(
    const float* __restrict__ params, const float* __restrict__ W_emb,
    const float* __restrict__ b_emb, const float* __restrict__ KT,
    const float* __restrict__ bT, const float* __restrict__ W1,
    const float* __restrict__ W2,
    f16x8* __restrict__ fragW1, f16x8* __restrict__ fragW2)
{
    __shared__ float s_emb[128];
    __shared__ float s_filt[36];      // [i2*3+j2][c]
    __shared__ float s_wc[1936];      // [dy][dx][c][f], 11x11x4x4
    const int t = threadIdx.x, b = blockIdx.x;

    if (t < 128) {
        float sv = b_emb[t];
#pragma unroll
        for (int p = 0; p < 8; ++p)
            sv = fmaf(params[b * 8 + p], W_emb[p * 128 + t], sv);
        s_emb[t] = silu_f(sv);
    }
    __syncthreads();
    if (t < 36) {
        const int ij = t >> 2, ff = t & 3;
        float sv = bT[ff];
        for (int c = 0; c < 128; ++c)
            sv = fmaf(s_emb[c], KT[(ij * 128 + c) * 4 + ff], sv);
        s_filt[t] = silu_f(sv);
    }
    __syncthreads();

    // composite Wc[dy][dx][c][f] = sum_{i2,j2} F[i2][j2][c] * W2[dy-i2][dx-j2][c][f]
    for (int i = t; i < 1936; i += 256) {
        const int f = i & 3, c = (i >> 2) & 3;
        const int dxy = i >> 4, dx = dxy % 11, dy = dxy / 11;
        float sv = 0.f;
#pragma unroll
        for (int i2 = 0; i2 < 3; ++i2)
#pragma unroll
            for (int j2 = 0; j2 < 3; ++j2) {
                const int a = dy - i2, bb = dx - j2;
                if (a >= 0 && a < 9 && bb >= 0 && bb < 9)
                    sv = fmaf(s_filt[(i2 * 3 + j2) * 4 + c],
                              W2[((a * 9 + bb) * 4 + c) * 4 + f], sv);
            }
        s_wc[i] = sv;
    }
    __syncthreads();

    // B-fragments for the composite (per batch)
    for (int fi = t; fi < 11 * 256; fi += 256) {
        const int dy = fi >> 8, rem = fi & 255;
        const int st = (rem >> 7) & 1, hl = (rem >> 6) & 1, lane = rem & 63;
        const int g = lane >> 4, n = lane & 15, s = n >> 2, f = n & 3;
        f16x8 v;
#pragma unroll
        for (int j = 0; j < 8; ++j) {
            const int k = st * 32 + g * 8 + j;
            const int e = k >> 2, c = k & 3, dx = e - s;
            const float wv = (dx >= 0 && dx < 11)
                ? s_wc[((dy * 11 + dx) * 4 + c) * 4 + f] : 0.f;
            const f16x2 hlv = split_f(wv);
            v[j] = hl ? hlv[1] : hlv[0];
        }
        fragW2[((size_t)b * 11 + dy) * 256 + rem] = v;
    }

    // B-fragments for W1 (batch-independent; block 0 only)
    if (b == 0) {
        for (int fi = t; fi < 9 * 256; fi += 256) {
            const int dy = fi >> 8, rem = fi & 255;
            const int st = (rem >> 7) & 1, hl = (rem >> 6) & 1, lane = rem & 63;
            const int g = lane >> 4, n = lane & 15, s = n >> 2, f = n & 3;
            f16x8 v;
#pragma unroll
            for (int j = 0; j < 8; ++j) {
                const int k = st * 32 + g * 8 + j;
                const int e = k >> 2, c = k & 3, dx = e - s;
                const float wv = (dx >= 0 && dx < 9)
                    ? W1[((dy * 9 + dx) * 4 + c) * 4 + f] : 0.f;
                const f16x2 hlv = split_f(wv);
                v[j] = hl ? hlv[1] : hlv[0];
            }
            fragW1[(size_t)dy * 256 + rem] = v;
        }
    }
}

// --- conv1: [16,512,512,4] f32 -> relu -> y1 [16,504,504] x (h,l)x4 f16
__global__ __launch_bounds__(256, 2) void k_conv1(
    const float* __restrict__ in, const float* __restrict__ b1,
    const f16x8* __restrict__ fragW1, f16* __restrict__ y1)
{
    __shared__ f16x4 s_hi[40][76];
    __shared__ f16x4 s_lo[40][76];
    const int t = threadIdx.x;
    const int x0 = blockIdx.x * 64, y0 = blockIdx.y * 32, b = blockIdx.z;

    const float4* inp = (const float4*)in + (size_t)b * (512 * 512);
    for (int i = t; i < 40 * 76; i += 256) {
        const int rr = i / 76, cc = i % 76;
        const int gy = y0 + rr, gx = x0 + cc;
        float4 v = make_float4(0.f, 0.f, 0.f, 0.f);
        if (gy < 512 && gx < 512) v = inp[gy * 512 + gx];
        f16x4 h, l;
        const f16x2 p0 = split_f(v.x), p1 = split_f(v.y);
        const f16x2 p2 = split_f(v.z), p3 = split_f(v.w);
        h[0] = p0[0]; l[0] = p0[1]; h[1] = p1[0]; l[1] = p1[1];
        h[2] = p2[0]; l[2] = p2[1]; h[3] = p3[0]; l[3] = p3[1];
        s_hi[rr][cc] = h; s_lo[rr][cc] = l;
    }

    const int lane = t & 63, w = t >> 6;
    const int g = lane >> 4, n = lane & 15, s = n >> 2, f = n & 3;

    __syncthreads();

    const float bias = b1[f];
    f32x4 acc[8];
#pragma unroll
    for (int r = 0; r < 8; ++r) acc[r] = (f32x4){bias, bias, bias, bias};

    const int ai = 4 * (lane & 15) + 2 * g;
#pragma unroll
    for (int st = 0; st < 2; ++st) {
        // all A-fragments for this K-half resident (16 x hi/lo x 4 VGPR)
        f16x8 Ah[16], Al[16];
#pragma unroll
        for (int ir = 0; ir < 16; ++ir) {
            Ah[ir] = *(const f16x8*)(&s_hi[w * 8 + ir][0] + ai + st * 8);
            Al[ir] = *(const f16x8*)(&s_lo[w * 8 + ir][0] + ai + st * 8);
        }
#pragma unroll
        for (int dy = 0; dy < 9; ++dy) {
            const f16x8 Bh = fragW1[dy * 256 + st * 128 + lane];
            const f16x8 Bl = fragW1[dy * 256 + st * 128 + 64 + lane];
#pragma unroll
            for (int r = 0; r < 8; ++r) {
                acc[r] = mfma16(Ah[r + dy], Bh, acc[r]);
                acc[r] = mfma16(Ah[r + dy], Bl, acc[r]);
                acc[r] = mfma16(Al[r + dy], Bh, acc[r]);
            }
        }
    }

    // D: col n=(s,f); row m=4g+q; x = x0+16g+4q+s; store (h,l) f16x2
    const int xb = x0 + 16 * g + s;
#pragma unroll
    for (int r = 0; r < 8; ++r) {
        const int yr = y0 + w * 8 + r;
        if (yr >= 504) continue;
        const size_t rowbase = ((size_t)(b * 504 + yr) * 504) * 8 + f * 2;
#pragma unroll
        for (int q = 0; q < 4; ++q) {
            const int x = xb + 4 * q;
            if (x < 504) {
                const float v = fmaxf(acc[r][q], 0.f);
                *(f16x2*)(y1 + rowbase + (size_t)x * 8) = split_f(v);
            }
        }
    }
}

// --- composite 11x11 per-batch conv on y1 + relu + pixnorm -> out f32
__global__ __launch_bounds__(256, 2) void k_dwconv2(
    const f16* __restrict__ y1, const float* __restrict__ b2,
    const f16x8* __restrict__ fragW2, float* __restrict__ out)
{
    __shared__ f16x4 s_hi[42][76];
    __shared__ f16x4 s_lo[42][76];
    const int t = threadIdx.x;
    const int x0 = blockIdx.x * 64, y0 = blockIdx.y * 32, b = blockIdx.z;

    // stage y1 with halo (-1 .. +9 beyond tile), zero outside [0,504)^2
    for (int i = t; i < 42 * 76; i += 256) {
        const int rr = i / 76, cc = i % 76;
        const int gy = y0 - 1 + rr, gx = x0 - 1 + cc;
        f16x4 h, l;
        if (gy >= 0 && gy < 504 && gx >= 0 && gx < 504) {
            const f16x8 p = *(const f16x8*)(y1 + ((size_t)(b * 504 + gy) * 504 +
                                                  (size_t)gx) * 8);
            h[0] = p[0]; l[0] = p[1]; h[1] = p[2]; l[1] = p[3];
            h[2] = p[4]; l[2] = p[5]; h[3] = p[6]; l[3] = p[7];
        } else {
            h[0] = h[1] = h[2] = h[3] = (f16)0.f;
            l[0] = l[1] = l[2] = l[3] = (f16)0.f;
        }
        s_hi[rr][cc] = h; s_lo[rr][cc] = l;
    }

    const int lane = t & 63, w = t >> 6;
    const int g = lane >> 4, n = lane & 15, s = n >> 2, f = n & 3;
    const f16x8* fr = fragW2 + (size_t)b * 11 * 256;

    __syncthreads();

    const float bias = b2[f];
    f32x4 acc[8];
#pragma unroll
    for (int r = 0; r < 8; ++r) acc[r] = (f32x4){bias, bias, bias, bias};

    const int ai = 4 * (lane & 15) + 2 * g;
#pragma unroll
    for (int st = 0; st < 2; ++st) {
        // all A-fragments for this K-half resident (18 x hi/lo x 4 VGPR)
        f16x8 Ah[18], Al[18];
#pragma unroll
        for (int ir = 0; ir < 18; ++ir) {
            Ah[ir] = *(const f16x8*)(&s_hi[w * 8 + ir][0] + ai + st * 8);
            Al[ir] = *(const f16x8*)(&s_lo[w * 8 + ir][0] + ai + st * 8);
        }
#pragma unroll
        for (int dy = 0; dy < 11; ++dy) {
            const f16x8 Bh = fr[dy * 256 + st * 128 + lane];
            const f16x8 Bl = fr[dy * 256 + st * 128 + 64 + lane];
#pragma unroll
            for (int r = 0; r < 8; ++r) {
                acc[r] = mfma16(Ah[r + dy], Bh, acc[r]);
                acc[r] = mfma16(Ah[r + dy], Bl, acc[r]);
                acc[r] = mfma16(Al[r + dy], Bh, acc[r]);
            }
        }
    }

    // epilogue: relu -> pixnorm across channels (lanes n^1, n^2) -> f32 store
    const int xb = x0 + 16 * g + s;
#pragma unroll
    for (int r = 0; r < 8; ++r) {
        const int yr = y0 + w * 8 + r;
        const size_t rowbase = ((size_t)((size_t)b * 496 + yr) * 496) * 4 + f;
#pragma unroll
        for (int q = 0; q < 4; ++q) {
            float v = fmaxf(acc[r][q], 0.f);
            float sq = v * v;
            sq += __shfl_xor(sq, 1);
            sq += __shfl_xor(sq, 2);
            const float sc = rsqrtf(sq * 0.25f + 1e-8f);
            const int x = xb + 4 * q;
            if (yr < 496 && x < 496) out[rowbase + (size_t)x * 4] = v * sc;
        }
    }
}

extern "C" void kernel_launch(void* const* d_in, const int* in_sizes, int n_in,
                              void* d_out, int out_size, void* d_ws, size_t ws_size,
                              hipStream_t stream)
{
    const float* noise  = (const float*)d_in[0];
    const float* params = (const float*)d_in[1];
    const float* W_emb  = (const float*)d_in[2];
    const float* b_emb  = (const float*)d_in[3];
    const float* KT     = (const float*)d_in[4];
    const float* bT     = (const float*)d_in[5];
    const float* W1     = (const float*)d_in[6];
    const float* b1     = (const float*)d_in[7];
    const float* W2     = (const float*)d_in[8];
    const float* b2     = (const float*)d_in[9];

    float* out = (float*)d_out;
    f16*   y1  = (f16*)d_ws;  // 16*504*504*8 f16 = 65,028,096 B
    f16x8* fragW2 = (f16x8*)((char*)d_ws + 65028096);           // 720,896 B
    f16x8* fragW1 = (f16x8*)((char*)d_ws + 65028096 + 720896);  //  36,864 B

    k_prep<<<dim3(16), dim3(256), 0, stream>>>(params, W_emb, b_emb, KT, bT,
                                               W1, W2, fragW1, fragW2);

    dim3 grid(8, 16, 16);   // ceil(504/64), ceil(504/32), B
    k_conv1<<<grid, dim3(256), 0, stream>>>(noise, b1, fragW1, y1);

    dim3 grid2(8, 16, 16);  // ceil(496/64), ceil(496/32), B
    k_dwconv2<<<grid2, dim3(256), 0, stream>>>(y1, b2, fragW2, out);
}